// Round 10
// baseline (2975.534 us; speedup 1.0000x reference)
//
#include <hip/hip_runtime.h>
#include <math.h>

#define GAMMA 0.5f

typedef __bf16 bf16x8 __attribute__((ext_vector_type(8)));
typedef float  f32x4  __attribute__((ext_vector_type(4)));

__device__ __forceinline__ unsigned short f2bf(float f){
  union { float ff; unsigned u; } x; x.ff = f;
  return (unsigned short)((x.u + 0x7fffu + ((x.u >> 16) & 1u)) >> 16);
}

__device__ __forceinline__ float bf2f(unsigned short u){
  union { unsigned u; float f; } x; x.u = (unsigned)u << 16;
  return x.f;
}

__device__ __forceinline__ float fast_tanh(float v){
  float e = __expf(v + v);
  return 1.f - 2.f * __builtin_amdgcn_rcpf(e + 1.f);
}

__device__ __forceinline__ void gload16(const void* g, void* l){
  __builtin_amdgcn_global_load_lds((const __attribute__((address_space(1))) void*)g,
                                   (__attribute__((address_space(3))) void*)l,
                                   16, 0, 0);
}

// ============================================================================
// gemm_bt: 2-barrier single-buffer GEMM, C = A[M,Ktot]*B[N,Ktot]^T.
// blockIdx.z selects a K-chunk of length K (split-K). Tile BM x BN, BK=64,
// 256 thr = 4 waves 2x2, wave owns WM x WN, acc [WM/16][WN/16] f32x4.
//
// r9-PROVEN addressing (keep exactly):
//  - BK=64 dual-optimal LDS slot map: 16B chunk (row, kq), kq in 0..7:
//    slot = (row>>2)*32 + (row&3)*8 + ((kq>>2)^((row>>2)&1))*4 + ((kq&3)^(row&3))
//    STAGE: 8 consecutive threads = one FULL row x 128B (coalesced, full
//    L2-line); ds_read_b128 0-conflict (r9: conflicts 4.7M -> 524K, FETCH
//    49 -> 24.8MB, MfmaUtil 26 -> 33%).
//  - LDS-packed bf16 epilogue (r6-proven: kills 1.9x write amplification).
// r10 change: WAVE-AREA REBALANCE. 64x64 waves = 32 FLOP/LDS-byte (LDS floor
// 20.5us > MFMA floor 16.5us for G1). 128x64 waves = 42.7 FLOP/byte -> LDS
// floor 15us, balanced. G1/G2 move to BM=256,BN=128 (2 blocks/CU, 48KB LDS).
// Pack epilogue runs in two 128-row halves (pack buf 32KB <= 48KB staging).
// K-loop: sync; STAGE; sync (drains vmcnt); COMPUTE x2. Ring/counted-vmcnt/
// 8-phase all measured worse on this problem (r1-r7).
// Epilogues:
//  MODE 0: F0=v; F1=v (f32)            MODE 3: masked f32 (head)
//  MODE 2: F0 = .5*F0 + .5*(v+R0)      (fallback path)
//  MODE 1: U0 = bf16(tanh(v+bias))     -- LDS-packed full rows
//  MODE 4: U0 = bf16(v), U0 += z*pstride ('nmax') -- LDS-packed
// ============================================================================
template<int MODE, int BM, int BN, int WM, int WN>
__global__ __launch_bounds__(256, 2)
void gemm_bt(const unsigned short* __restrict__ A,
             const unsigned short* __restrict__ B,
             int K, int lda, int ldb, const float* __restrict__ bias,
             int ldc, int nmax, int RM, int MR, int RN,
             float* __restrict__ F0, float* __restrict__ F1,
             unsigned short* __restrict__ U0,
             const float* __restrict__ R0)
{
  static_assert(BM / WM == 2 && BN / WN == 2, "4 waves arranged 2x2");
  static_assert((MODE != 1 && MODE != 4) || WM == 128, "pack assumes WM=128");
  constexpr int MI = WM / 16;
  constexpr int JN = WN / 16;
  const int bid = blockIdx.y * gridDim.x + blockIdx.x;
  const int xcd = bid & 7, kk = bid >> 3;
  const int m0 = ((xcd % MR) * RM + (kk % RM)) * BM;
  const int n0 = ((xcd / MR) * RN + (kk / RM)) * BN;
  const long kz = (long)blockIdx.z * K;
  A += kz; B += kz;
  if (MODE == 4) U0 += (long)blockIdx.z * (long)nmax;

  const int t = threadIdx.x, w = t >> 6, l = t & 63;

  constexpr int STG = (BM + BN) * 64;                               // staging u16
  constexpr int PCK = (MODE == 1 || MODE == 4) ? 128 * BN : 0;      // half-pack u16
  constexpr int SH  = STG > PCK ? STG : PCK;
  __shared__ __align__(16) unsigned short sh[SH];
  unsigned short* lgA = sh;            // [BM*64]  (BM rows x 8 chunks x 8 u16)
  unsigned short* lgB = sh + BM * 64;  // [BN*64]

  f32x4 acc[MI][JN];
  #pragma unroll
  for (int i = 0; i < MI; i++)
    #pragma unroll
    for (int j = 0; j < JN; j++) acc[i][j] = (f32x4){0.f, 0.f, 0.f, 0.f};

  const int wm = (w & 1) * WM, wn = (w >> 1) * WN;
  const int lr = l & 15, quad = l >> 4;
  // fragment-read slot offset within a 128-slot row-group (const per thread):
  const int fo0 = (lr >> 2) * 32 + (lr & 3) * 8 + ((lr >> 2) & 1) * 4 + (quad ^ (lr & 3));
  const int fo1 = fo0 ^ 4;

  // STAGE: thread c handles slot c; inverse map gives its global chunk:
  //   row = (c>>5)*4 + ((c>>3)&3)
  //   ko  = ((((c>>2)&1) ^ ((c>>5)&1))*4 + ((c&3) ^ ((c>>3)&3))) * 8
#define STAGE(kt) { \
    _Pragma("unroll") \
    for (int j = 0; j < BM / 32; j++) { \
      const int c = j * 256 + t; \
      const int a = (c >> 3) & 3; \
      const int row = (c >> 5) * 4 + a; \
      const int ko = ((((c >> 2) & 1) ^ ((c >> 5) & 1)) << 5) + (((c & 3) ^ a) << 3); \
      gload16(A + (long)(m0 + row) * lda + (kt) + ko, (char*)lgA + c * 16); \
    } \
    _Pragma("unroll") \
    for (int j = 0; j < BN / 32; j++) { \
      const int c = j * 256 + t; \
      const int a = (c >> 3) & 3; \
      const int row = (c >> 5) * 4 + a; \
      const int ko = ((((c >> 2) & 1) ^ ((c >> 5) & 1)) << 5) + (((c & 3) ^ a) << 3); \
      gload16(B + (long)(n0 + row) * ldb + (kt) + ko, (char*)lgB + c * 16); \
    } }

#define COMPUTE(fo) { \
    bf16x8 af[MI], bg[JN]; \
    _Pragma("unroll") \
    for (int i = 0; i < MI; i++) \
      af[i] = *(const bf16x8*)&lgA[((((wm >> 4) + i) << 7) + (fo)) * 8]; \
    _Pragma("unroll") \
    for (int j = 0; j < JN; j++) \
      bg[j] = *(const bf16x8*)&lgB[((((wn >> 4) + j) << 7) + (fo)) * 8]; \
    _Pragma("unroll") \
    for (int i = 0; i < MI; i++) \
      _Pragma("unroll") \
      for (int j = 0; j < JN; j++) \
        acc[i][j] = __builtin_amdgcn_mfma_f32_16x16x32_bf16(af[i], bg[j], acc[i][j], 0, 0, 0); \
  }

  const int NT = K >> 6;               // BK=64 steps (K multiple of 64)
  for (int tt = 0; tt < NT; ++tt) {
    __syncthreads();                   // prev COMPUTE's LDS reads done
    STAGE(tt * 64)
    __syncthreads();                   // compiler drains vmcnt: staged data ready
    COMPUTE(fo0)
    COMPUTE(fo1)
  }
#undef STAGE
#undef COMPUTE

  if constexpr (MODE == 1 || MODE == 4) {
    // ---- LDS-packed bf16 epilogue, in 128-row halves (reuses staging LDS).
    #pragma unroll
    for (int hh = 0; hh < BM / 128; hh++) {
      __syncthreads();                 // LDS free (loop reads / prev write done)
      if (wm == hh * 128) {            // the 2 waves owning these rows pack
        #pragma unroll
        for (int i = 0; i < MI; i++) {
          const int rb = i * 16 + quad * 4;   // local row within half
          #pragma unroll
          for (int j = 0; j < JN; j++) {
            const int cl = wn + j * 16 + lr;
            const float bia = (MODE == 1) ? bias[n0 + cl] : 0.f;
            #pragma unroll
            for (int r = 0; r < 4; r++) {
              const float v = acc[i][j][r] + bia;
              sh[(rb + r) * BN + cl] = (MODE == 1) ? f2bf(fast_tanh(v)) : f2bf(v);
            }
          }
        }
      }
      __syncthreads();
      constexpr int CPR = BN / 8;      // 16B chunks per row
      constexpr int RPP = 256 / CPR;   // rows per pass
      const int ch = t & (CPR - 1), rw = t / CPR;
      #pragma unroll
      for (int p = 0; p < 128 / RPP; p++) {
        const int row = p * RPP + rw;
        *(bf16x8*)&U0[(long)(m0 + hh * 128 + row) * ldc + n0 + ch * 8] =
            *(const bf16x8*)&sh[row * BN + ch * 8];
      }
    }
  } else {
    #pragma unroll
    for (int i = 0; i < MI; i++) {
      const int mb = m0 + wm + i * 16 + quad * 4;
      #pragma unroll
      for (int j = 0; j < JN; j++) {
        const int n = n0 + wn + j * 16 + lr;
        float bia = 0.f;
        if (MODE == 3) { if (n < nmax) bia = bias[n]; } else { bia = bias[n]; }
        #pragma unroll
        for (int r = 0; r < 4; r++) {
          const long m = mb + r;
          const float v = acc[i][j][r] + bia;
          const long idx = m * (long)ldc + n;
          if (MODE == 0)      { F0[idx] = v; F1[idx] = v; }
          else if (MODE == 2) { F0[idx] = (1.f - GAMMA) * F0[idx] + GAMMA * (v + R0[idx]); }
          else                { if (n < nmax) F0[idx] = v; }
        }
      }
    }
  }
}

// LayerNorm over rows of 1024 fp32 -> bf16. COMB=1 first folds the split-K
// combine: h <- .5h + .5*(sum_z P[z] + b2 + xemb)  (P is bf16), writes h,
// then LNs the NEW h (matches reference step ordering; validated r3-r9).
template<int COMB>
__global__ __launch_bounds__(256)
void ln_bf16(float* __restrict__ h, const float* __restrict__ gw,
             const float* __restrict__ gb, unsigned short* __restrict__ o,
             const float* __restrict__ xemb, const float* __restrict__ b2,
             const unsigned short* __restrict__ P, long ps)
{
  const int row = blockIdx.x, t = threadIdx.x;
  const long base = (long)row * 1024;
  float4 v = ((const float4*)(h + base))[t];
  if (COMB) {
    const ushort4 q0 = *(const ushort4*)&P[base + 4 * t];
    const ushort4 q1 = *(const ushort4*)&P[ps + base + 4 * t];
    const ushort4 q2 = *(const ushort4*)&P[2 * ps + base + 4 * t];
    const ushort4 q3 = *(const ushort4*)&P[3 * ps + base + 4 * t];
    const float4 xe = ((const float4*)(xemb + base))[t];
    const float4 bb = ((const float4*)b2)[t];
    v.x = (1.f - GAMMA) * v.x + GAMMA * (bf2f(q0.x) + bf2f(q1.x) + bf2f(q2.x) + bf2f(q3.x) + xe.x + bb.x);
    v.y = (1.f - GAMMA) * v.y + GAMMA * (bf2f(q0.y) + bf2f(q1.y) + bf2f(q2.y) + bf2f(q3.y) + xe.y + bb.y);
    v.z = (1.f - GAMMA) * v.z + GAMMA * (bf2f(q0.z) + bf2f(q1.z) + bf2f(q2.z) + bf2f(q3.z) + xe.z + bb.z);
    v.w = (1.f - GAMMA) * v.w + GAMMA * (bf2f(q0.w) + bf2f(q1.w) + bf2f(q2.w) + bf2f(q3.w) + xe.w + bb.w);
    ((float4*)(h + base))[t] = v;
  }
  float s = v.x + v.y + v.z + v.w;
  float q = v.x * v.x + v.y * v.y + v.z * v.z + v.w * v.w;
  #pragma unroll
  for (int o2 = 32; o2 > 0; o2 >>= 1) { s += __shfl_xor(s, o2); q += __shfl_xor(q, o2); }
  __shared__ float rs[4], rq[4];
  if ((t & 63) == 0) { rs[t >> 6] = s; rq[t >> 6] = q; }
  __syncthreads();
  s = rs[0] + rs[1] + rs[2] + rs[3];
  q = rq[0] + rq[1] + rq[2] + rq[3];
  const float mu  = s * (1.f / 1024.f);
  const float inv = rsqrtf(q * (1.f / 1024.f) - mu * mu + 1e-5f);
  const float4 wv = ((const float4*)gw)[t];
  const float4 bv = ((const float4*)gb)[t];
  ushort4 u;
  u.x = f2bf((v.x - mu) * inv * wv.x + bv.x);
  u.y = f2bf((v.y - mu) * inv * wv.y + bv.y);
  u.z = f2bf((v.z - mu) * inv * wv.z + bv.z);
  u.w = f2bf((v.w - mu) * inv * wv.w + bv.w);
  ((ushort4*)(o + base))[t] = u;
}

// f32 -> bf16 with zero padding
__global__ __launch_bounds__(256)
void cvt_pad(const float* __restrict__ src, unsigned short* __restrict__ dst,
             int src_rows, int src_cols, int dst_cols)
{
  const int r = blockIdx.y;
  const int c = blockIdx.x * 256 + threadIdx.x;
  if (c >= dst_cols) return;
  unsigned short v = 0;
  if (r < src_rows && c < src_cols) v = f2bf(src[(long)r * src_cols + c]);
  dst[(long)r * dst_cols + c] = v;
}

// h fp32 -> bf16; COMB=1 applies the final split-K combine first (P bf16).
template<int COMB>
__global__ __launch_bounds__(256)
void cvt_h(const float* __restrict__ h, unsigned short* __restrict__ o,
           const float* __restrict__ xemb, const float* __restrict__ b2,
           const unsigned short* __restrict__ P, long ps)
{
  const long i = (long)blockIdx.x * 256 + threadIdx.x;
  float4 v = ((const float4*)h)[i];
  if (COMB) {
    const ushort4 q0 = *(const ushort4*)&P[4 * i];
    const ushort4 q1 = *(const ushort4*)&P[ps + 4 * i];
    const ushort4 q2 = *(const ushort4*)&P[2 * ps + 4 * i];
    const ushort4 q3 = *(const ushort4*)&P[3 * ps + 4 * i];
    const float4 xe = ((const float4*)xemb)[i];
    const float4 bb = ((const float4*)b2)[(int)(i & 255)];
    v.x = (1.f - GAMMA) * v.x + GAMMA * (bf2f(q0.x) + bf2f(q1.x) + bf2f(q2.x) + bf2f(q3.x) + xe.x + bb.x);
    v.y = (1.f - GAMMA) * v.y + GAMMA * (bf2f(q0.y) + bf2f(q1.y) + bf2f(q2.y) + bf2f(q3.y) + xe.y + bb.y);
    v.z = (1.f - GAMMA) * v.z + GAMMA * (bf2f(q0.z) + bf2f(q1.z) + bf2f(q2.z) + bf2f(q3.z) + xe.z + bb.z);
    v.w = (1.f - GAMMA) * v.w + GAMMA * (bf2f(q0.w) + bf2f(q1.w) + bf2f(q2.w) + bf2f(q3.w) + xe.w + bb.w);
  }
  ushort4 u;
  u.x = f2bf(v.x); u.y = f2bf(v.y); u.z = f2bf(v.z); u.w = f2bf(v.w);
  ((ushort4*)o)[i] = u;
}

extern "C" void kernel_launch(void* const* d_in, const int* in_sizes, int n_in,
                              void* d_out, int out_size, void* d_ws, size_t ws_size,
                              hipStream_t stream)
{
  const float* x       = (const float*)d_in[0];
  const float* embed_w = (const float*)d_in[1];
  const float* embed_b = (const float*)d_in[2];
  const float* W1_w    = (const float*)d_in[3];
  const float* W1_b    = (const float*)d_in[4];
  const float* W2_w    = (const float*)d_in[5];
  const float* W2_b    = (const float*)d_in[6];
  const float* norm_w  = (const float*)d_in[7];
  const float* norm_b  = (const float*)d_in[8];
  const float* head_w  = (const float*)d_in[9];
  const float* head_b  = (const float*)d_in[10];
  (void)in_sizes; (void)n_in; (void)out_size;

  // Workspace layout (x/embW K-padded to 832 = 13*64 for BK=64)
  char* ws = (char*)d_ws;
  unsigned short* W1b  = (unsigned short*)(ws);              //  8,388,608  W1 bf16   [4096][1024]
  unsigned short* W2b  = (unsigned short*)(ws + 8388608);    //  8,388,608  W2 bf16   [1024][4096]
  unsigned short* xb   = (unsigned short*)(ws + 16777216);   //  6,815,744  x bf16    [4096][832]
  unsigned short* ewb  = (unsigned short*)(ws + 23592960);   //  1,703,936  embW bf16 [1024][832]
  unsigned short* hwb  = (unsigned short*)(ws + 25296896);   //  2,097,152  headW bf16[1024][1024]
  float*          xemb = (float*)(ws + 27394048);            // 16,777,216  x_emb f32 [4096][1024]
  float*          h    = (float*)(ws + 44171264);            // 16,777,216  h f32     [4096][1024]
  unsigned short* hn   = (unsigned short*)(ws + 60948480);   //  8,388,608  ln(h) bf16[4096][1024]
  unsigned short* act  = (unsigned short*)(ws + 69337088);   // 33,554,432  ffn act   [4096][4096]
  unsigned short* hb   = (unsigned short*)(ws + 102891520);  //  8,388,608  h bf16    [4096][1024]
  unsigned short* P    = (unsigned short*)(ws + 111280128);  // 33,554,432  partials bf16 [4][4096][1024]
  const bool splitk = ws_size >= (size_t)144834560;
  const long PS = 4194304;  // partial stride in u16 elements (4096*1024)

  cvt_pad<<<dim3(4, 4096), 256, 0, stream>>>(W1_w, W1b, 4096, 1024, 1024);
  cvt_pad<<<dim3(16, 1024), 256, 0, stream>>>(W2_w, W2b, 1024, 4096, 4096);
  cvt_pad<<<dim3(4, 4096), 256, 0, stream>>>(x, xb, 4096, 784, 832);
  cvt_pad<<<dim3(4, 1024), 256, 0, stream>>>(embed_w, ewb, 1024, 784, 832);
  cvt_pad<<<dim3(4, 1024), 256, 0, stream>>>(head_w, hwb, 1000, 1024, 1024);

  // x_emb = x @ embed_w^T + embed_b ; h = x_emb   (K=832)
  gemm_bt<0, 128, 128, 64, 64><<<dim3(8, 32), 256, 0, stream>>>(
      xb, ewb, 832, 832, 832, embed_b, 1024, 1024, 8, 4, 4, xemb, h, nullptr, nullptr);

  for (int s = 0; s < 30; s++) {
    if (splitk && s > 0)
      ln_bf16<1><<<4096, 256, 0, stream>>>(h, norm_w, norm_b, hn, xemb, W2_b, P, PS);
    else
      ln_bf16<0><<<4096, 256, 0, stream>>>(h, norm_w, norm_b, hn, nullptr, nullptr, nullptr, 0);

    // act = tanh(hn @ W1^T + b1): 256x128 tile, 128x64 waves (42.7 FLOP/LDS-B)
    // m-tiles 16, n-tiles 32; grid 512 = 2/CU; regions 4x2 of 4x16
    gemm_bt<1, 256, 128, 128, 64><<<dim3(32, 16), 256, 0, stream>>>(
        hn, W1b, 1024, 1024, 1024, W1_b, 4096, 4096, 4, 4, 16, nullptr, nullptr, act, nullptr);

    if (splitk) {
      // P[z] = act[:, z*1024:+1024] @ W2^T chunk (bf16, packed store):
      // 256x128 tile; per z: m-tiles 16, n-tiles 8; grid 512 = 2/CU
      gemm_bt<4, 256, 128, 128, 64><<<dim3(8, 16, 4), 256, 0, stream>>>(
          act, W2b, 1024, 4096, 4096, nullptr, 1024, (int)PS, 4, 4, 4,
          nullptr, nullptr, P, nullptr);
    } else {
      // fallback: h = .5h + .5(act @ W2^T + b2 + xemb) direct RMW
      gemm_bt<2, 128, 64, 64, 32><<<dim3(16, 32), 256, 0, stream>>>(
          act, W2b, 4096, 4096, 4096, W2_b, 1024, 1024, 8, 4, 8, h, nullptr, nullptr, xemb);
    }
  }

  if (splitk)
    cvt_h<1><<<4096, 256, 0, stream>>>(h, hb, xemb, W2_b, P, PS);
  else
    cvt_h<0><<<4096, 256, 0, stream>>>(h, hb, nullptr, nullptr, nullptr, 0);

  gemm_bt<3, 128, 128, 64, 64><<<dim3(8, 32), 256, 0, stream>>>(
      hb, hwb, 1024, 1024, 1024, head_b, 1000, 1000, 8, 4, 4, (float*)d_out, nullptr, nullptr, nullptr);
}

// Round 11
// 2863.043 us; speedup vs baseline: 1.0393x; 1.0393x over previous
//
#include <hip/hip_runtime.h>
#include <math.h>

#define GAMMA 0.5f

typedef __bf16 bf16x8 __attribute__((ext_vector_type(8)));
typedef float  f32x4  __attribute__((ext_vector_type(4)));

__device__ __forceinline__ unsigned short f2bf(float f){
  union { float ff; unsigned u; } x; x.ff = f;
  return (unsigned short)((x.u + 0x7fffu + ((x.u >> 16) & 1u)) >> 16);
}

__device__ __forceinline__ float bf2f(unsigned short u){
  union { unsigned u; float f; } x; x.u = (unsigned)u << 16;
  return x.f;
}

__device__ __forceinline__ float fast_tanh(float v){
  float e = __expf(v + v);
  return 1.f - 2.f * __builtin_amdgcn_rcpf(e + 1.f);
}

__device__ __forceinline__ void gload16(const void* g, void* l){
  __builtin_amdgcn_global_load_lds((const __attribute__((address_space(1))) void*)g,
                                   (__attribute__((address_space(3))) void*)l,
                                   16, 0, 0);
}

// ============================================================================
// gemm_bt: 2-barrier single-buffer GEMM, C = A[M,Ktot]*B[N,Ktot]^T.
// blockIdx.z selects a K-chunk of length K (split-K). Tile BM x BN, BK=64,
// TH threads = TH/64 waves arranged (BM/WM) x (BN/WN); wave owns WM x WN.
//
// PROVEN pieces (keep exactly):
//  - BK=64 dual-optimal LDS slot map (r9: conflicts 4.7M->524K, FETCH
//    49->24.8MB, MfmaUtil 26->33%): 16B chunk (row, kq), kq in 0..7:
//    slot = (row>>2)*32 + (row&3)*8 + ((kq>>2)^((row>>2)&1))*4 + ((kq&3)^(row&3))
//    STAGE: 8 consecutive threads = one FULL row x 128B; ds_read_b128
//    0-conflict. Lane-indexed fo formulas are thread-count-agnostic.
//  - LDS-packed bf16 epilogue (r6: kills 1.9x write amplification).
//  - 2-barrier loop at 4 blocks/CU (r10: dropping to 2 blocks/CU loses even
//    with better FLOP/LDS ratio -- block-level overlap dominates).
// r11 change (G1 only, within-run A/B vs G2 control): 128^2 tile with TWO
// waves of 64x128 (TH=128) instead of four of 64x64. FLOP/LDS-byte 32->42.7
// (LDS floor 20.6->15.5us) while grid stays 1024 = 4 blocks/CU.
// Epilogues:
//  MODE 0: F0=v; F1=v (f32)            MODE 3: masked f32 (head)
//  MODE 2: F0 = .5*F0 + .5*(v+R0)      (fallback path)
//  MODE 1: U0 = bf16(tanh(v+bias))     -- LDS-packed full rows
//  MODE 4: U0 = bf16(v), U0 += z*pstride ('nmax') -- LDS-packed
// ============================================================================
template<int MODE, int BM, int BN, int WM, int WN, int TH>
__global__ __launch_bounds__(TH, 2)
void gemm_bt(const unsigned short* __restrict__ A,
             const unsigned short* __restrict__ B,
             int K, int lda, int ldb, const float* __restrict__ bias,
             int ldc, int nmax, int RM, int MR, int RN,
             float* __restrict__ F0, float* __restrict__ F1,
             unsigned short* __restrict__ U0,
             const float* __restrict__ R0)
{
  constexpr int WMC = BM / WM;         // waves along M
  constexpr int WNC = BN / WN;         // waves along N
  static_assert(WMC * WNC * 64 == TH, "wave arrangement must fill block");
  constexpr int MI = WM / 16;
  constexpr int JN = WN / 16;
  const int bid = blockIdx.y * gridDim.x + blockIdx.x;
  const int xcd = bid & 7, kk = bid >> 3;
  const int m0 = ((xcd % MR) * RM + (kk % RM)) * BM;
  const int n0 = ((xcd / MR) * RN + (kk / RM)) * BN;
  const long kz = (long)blockIdx.z * K;
  A += kz; B += kz;
  if (MODE == 4) U0 += (long)blockIdx.z * (long)nmax;

  const int t = threadIdx.x, w = t >> 6, l = t & 63;

  constexpr int STG = (BM + BN) * 64;                         // staging u16
  constexpr int PCK = (MODE == 1 || MODE == 4) ? BM * BN : 0; // pack u16
  constexpr int SH  = STG > PCK ? STG : PCK;
  __shared__ __align__(16) unsigned short sh[SH];
  unsigned short* lgA = sh;            // [BM*64]  (BM rows x 8 chunks x 8 u16)
  unsigned short* lgB = sh + BM * 64;  // [BN*64]

  f32x4 acc[MI][JN];
  #pragma unroll
  for (int i = 0; i < MI; i++)
    #pragma unroll
    for (int j = 0; j < JN; j++) acc[i][j] = (f32x4){0.f, 0.f, 0.f, 0.f};

  const int wm = (w % WMC) * WM, wn = (w / WMC) * WN;
  const int lr = l & 15, quad = l >> 4;
  // fragment-read slot offset within a 128-slot row-group (const per thread):
  const int fo0 = (lr >> 2) * 32 + (lr & 3) * 8 + ((lr >> 2) & 1) * 4 + (quad ^ (lr & 3));
  const int fo1 = fo0 ^ 4;

  // STAGE: thread c handles slot c; inverse map gives its global chunk:
  //   row = (c>>5)*4 + ((c>>3)&3)
  //   ko  = ((((c>>2)&1) ^ ((c>>5)&1))*4 + ((c&3) ^ ((c>>3)&3))) * 8
#define STAGE(kt) { \
    _Pragma("unroll") \
    for (int j = 0; j < (BM * 8) / TH; j++) { \
      const int c = j * TH + t; \
      const int a = (c >> 3) & 3; \
      const int row = (c >> 5) * 4 + a; \
      const int ko = ((((c >> 2) & 1) ^ ((c >> 5) & 1)) << 5) + (((c & 3) ^ a) << 3); \
      gload16(A + (long)(m0 + row) * lda + (kt) + ko, (char*)lgA + c * 16); \
    } \
    _Pragma("unroll") \
    for (int j = 0; j < (BN * 8) / TH; j++) { \
      const int c = j * TH + t; \
      const int a = (c >> 3) & 3; \
      const int row = (c >> 5) * 4 + a; \
      const int ko = ((((c >> 2) & 1) ^ ((c >> 5) & 1)) << 5) + (((c & 3) ^ a) << 3); \
      gload16(B + (long)(n0 + row) * ldb + (kt) + ko, (char*)lgB + c * 16); \
    } }

#define COMPUTE(fo) { \
    bf16x8 af[MI], bg[JN]; \
    _Pragma("unroll") \
    for (int i = 0; i < MI; i++) \
      af[i] = *(const bf16x8*)&lgA[((((wm >> 4) + i) << 7) + (fo)) * 8]; \
    _Pragma("unroll") \
    for (int j = 0; j < JN; j++) \
      bg[j] = *(const bf16x8*)&lgB[((((wn >> 4) + j) << 7) + (fo)) * 8]; \
    _Pragma("unroll") \
    for (int i = 0; i < MI; i++) \
      _Pragma("unroll") \
      for (int j = 0; j < JN; j++) \
        acc[i][j] = __builtin_amdgcn_mfma_f32_16x16x32_bf16(af[i], bg[j], acc[i][j], 0, 0, 0); \
  }

  const int NT = K >> 6;               // BK=64 steps (K multiple of 64)
  for (int tt = 0; tt < NT; ++tt) {
    __syncthreads();                   // prev COMPUTE's LDS reads done
    STAGE(tt * 64)
    __syncthreads();                   // compiler drains vmcnt: staged data ready
    COMPUTE(fo0)
    COMPUTE(fo1)
  }
#undef STAGE
#undef COMPUTE

  if constexpr (MODE == 1 || MODE == 4) {
    // ---- LDS-packed bf16 epilogue: assemble [BM][BN] tile, write full rows.
    __syncthreads();                   // last COMPUTE's reads done; reuse sh
    #pragma unroll
    for (int i = 0; i < MI; i++) {
      const int rb = wm + i * 16 + quad * 4;
      #pragma unroll
      for (int j = 0; j < JN; j++) {
        const int cl = wn + j * 16 + lr;
        const float bia = (MODE == 1) ? bias[n0 + cl] : 0.f;
        #pragma unroll
        for (int r = 0; r < 4; r++) {
          const float v = acc[i][j][r] + bia;
          sh[(rb + r) * BN + cl] = (MODE == 1) ? f2bf(fast_tanh(v)) : f2bf(v);
        }
      }
    }
    __syncthreads();
    constexpr int CPR = BN / 8;        // 16B chunks per row
    constexpr int RPP = TH / CPR;      // rows per pass
    const int ch = t & (CPR - 1), rw = t / CPR;
    #pragma unroll
    for (int p = 0; p < BM / RPP; p++) {
      const int row = p * RPP + rw;
      *(bf16x8*)&U0[(long)(m0 + row) * ldc + n0 + ch * 8] =
          *(const bf16x8*)&sh[row * BN + ch * 8];
    }
  } else {
    #pragma unroll
    for (int i = 0; i < MI; i++) {
      const int mb = m0 + wm + i * 16 + quad * 4;
      #pragma unroll
      for (int j = 0; j < JN; j++) {
        const int n = n0 + wn + j * 16 + lr;
        float bia = 0.f;
        if (MODE == 3) { if (n < nmax) bia = bias[n]; } else { bia = bias[n]; }
        #pragma unroll
        for (int r = 0; r < 4; r++) {
          const long m = mb + r;
          const float v = acc[i][j][r] + bia;
          const long idx = m * (long)ldc + n;
          if (MODE == 0)      { F0[idx] = v; F1[idx] = v; }
          else if (MODE == 2) { F0[idx] = (1.f - GAMMA) * F0[idx] + GAMMA * (v + R0[idx]); }
          else                { if (n < nmax) F0[idx] = v; }
        }
      }
    }
  }
}

// LayerNorm over rows of 1024 fp32 -> bf16. COMB=1 first folds the split-K
// combine: h <- .5h + .5*(sum_z P[z] + b2 + xemb)  (P is bf16), writes h,
// then LNs the NEW h (matches reference step ordering; validated r3-r10).
template<int COMB>
__global__ __launch_bounds__(256)
void ln_bf16(float* __restrict__ h, const float* __restrict__ gw,
             const float* __restrict__ gb, unsigned short* __restrict__ o,
             const float* __restrict__ xemb, const float* __restrict__ b2,
             const unsigned short* __restrict__ P, long ps)
{
  const int row = blockIdx.x, t = threadIdx.x;
  const long base = (long)row * 1024;
  float4 v = ((const float4*)(h + base))[t];
  if (COMB) {
    const ushort4 q0 = *(const ushort4*)&P[base + 4 * t];
    const ushort4 q1 = *(const ushort4*)&P[ps + base + 4 * t];
    const ushort4 q2 = *(const ushort4*)&P[2 * ps + base + 4 * t];
    const ushort4 q3 = *(const ushort4*)&P[3 * ps + base + 4 * t];
    const float4 xe = ((const float4*)(xemb + base))[t];
    const float4 bb = ((const float4*)b2)[t];
    v.x = (1.f - GAMMA) * v.x + GAMMA * (bf2f(q0.x) + bf2f(q1.x) + bf2f(q2.x) + bf2f(q3.x) + xe.x + bb.x);
    v.y = (1.f - GAMMA) * v.y + GAMMA * (bf2f(q0.y) + bf2f(q1.y) + bf2f(q2.y) + bf2f(q3.y) + xe.y + bb.y);
    v.z = (1.f - GAMMA) * v.z + GAMMA * (bf2f(q0.z) + bf2f(q1.z) + bf2f(q2.z) + bf2f(q3.z) + xe.z + bb.z);
    v.w = (1.f - GAMMA) * v.w + GAMMA * (bf2f(q0.w) + bf2f(q1.w) + bf2f(q2.w) + bf2f(q3.w) + xe.w + bb.w);
    ((float4*)(h + base))[t] = v;
  }
  float s = v.x + v.y + v.z + v.w;
  float q = v.x * v.x + v.y * v.y + v.z * v.z + v.w * v.w;
  #pragma unroll
  for (int o2 = 32; o2 > 0; o2 >>= 1) { s += __shfl_xor(s, o2); q += __shfl_xor(q, o2); }
  __shared__ float rs[4], rq[4];
  if ((t & 63) == 0) { rs[t >> 6] = s; rq[t >> 6] = q; }
  __syncthreads();
  s = rs[0] + rs[1] + rs[2] + rs[3];
  q = rq[0] + rq[1] + rq[2] + rq[3];
  const float mu  = s * (1.f / 1024.f);
  const float inv = rsqrtf(q * (1.f / 1024.f) - mu * mu + 1e-5f);
  const float4 wv = ((const float4*)gw)[t];
  const float4 bv = ((const float4*)gb)[t];
  ushort4 u;
  u.x = f2bf((v.x - mu) * inv * wv.x + bv.x);
  u.y = f2bf((v.y - mu) * inv * wv.y + bv.y);
  u.z = f2bf((v.z - mu) * inv * wv.z + bv.z);
  u.w = f2bf((v.w - mu) * inv * wv.w + bv.w);
  ((ushort4*)(o + base))[t] = u;
}

// f32 -> bf16 with zero padding
__global__ __launch_bounds__(256)
void cvt_pad(const float* __restrict__ src, unsigned short* __restrict__ dst,
             int src_rows, int src_cols, int dst_cols)
{
  const int r = blockIdx.y;
  const int c = blockIdx.x * 256 + threadIdx.x;
  if (c >= dst_cols) return;
  unsigned short v = 0;
  if (r < src_rows && c < src_cols) v = f2bf(src[(long)r * src_cols + c]);
  dst[(long)r * dst_cols + c] = v;
}

// h fp32 -> bf16; COMB=1 applies the final split-K combine first (P bf16).
template<int COMB>
__global__ __launch_bounds__(256)
void cvt_h(const float* __restrict__ h, unsigned short* __restrict__ o,
           const float* __restrict__ xemb, const float* __restrict__ b2,
           const unsigned short* __restrict__ P, long ps)
{
  const long i = (long)blockIdx.x * 256 + threadIdx.x;
  float4 v = ((const float4*)h)[i];
  if (COMB) {
    const ushort4 q0 = *(const ushort4*)&P[4 * i];
    const ushort4 q1 = *(const ushort4*)&P[ps + 4 * i];
    const ushort4 q2 = *(const ushort4*)&P[2 * ps + 4 * i];
    const ushort4 q3 = *(const ushort4*)&P[3 * ps + 4 * i];
    const float4 xe = ((const float4*)xemb)[i];
    const float4 bb = ((const float4*)b2)[(int)(i & 255)];
    v.x = (1.f - GAMMA) * v.x + GAMMA * (bf2f(q0.x) + bf2f(q1.x) + bf2f(q2.x) + bf2f(q3.x) + xe.x + bb.x);
    v.y = (1.f - GAMMA) * v.y + GAMMA * (bf2f(q0.y) + bf2f(q1.y) + bf2f(q2.y) + bf2f(q3.y) + xe.y + bb.y);
    v.z = (1.f - GAMMA) * v.z + GAMMA * (bf2f(q0.z) + bf2f(q1.z) + bf2f(q2.z) + bf2f(q3.z) + xe.z + bb.z);
    v.w = (1.f - GAMMA) * v.w + GAMMA * (bf2f(q0.w) + bf2f(q1.w) + bf2f(q2.w) + bf2f(q3.w) + xe.w + bb.w);
  }
  ushort4 u;
  u.x = f2bf(v.x); u.y = f2bf(v.y); u.z = f2bf(v.z); u.w = f2bf(v.w);
  ((ushort4*)o)[i] = u;
}

extern "C" void kernel_launch(void* const* d_in, const int* in_sizes, int n_in,
                              void* d_out, int out_size, void* d_ws, size_t ws_size,
                              hipStream_t stream)
{
  const float* x       = (const float*)d_in[0];
  const float* embed_w = (const float*)d_in[1];
  const float* embed_b = (const float*)d_in[2];
  const float* W1_w    = (const float*)d_in[3];
  const float* W1_b    = (const float*)d_in[4];
  const float* W2_w    = (const float*)d_in[5];
  const float* W2_b    = (const float*)d_in[6];
  const float* norm_w  = (const float*)d_in[7];
  const float* norm_b  = (const float*)d_in[8];
  const float* head_w  = (const float*)d_in[9];
  const float* head_b  = (const float*)d_in[10];
  (void)in_sizes; (void)n_in; (void)out_size;

  // Workspace layout (x/embW K-padded to 832 = 13*64 for BK=64)
  char* ws = (char*)d_ws;
  unsigned short* W1b  = (unsigned short*)(ws);              //  8,388,608  W1 bf16   [4096][1024]
  unsigned short* W2b  = (unsigned short*)(ws + 8388608);    //  8,388,608  W2 bf16   [1024][4096]
  unsigned short* xb   = (unsigned short*)(ws + 16777216);   //  6,815,744  x bf16    [4096][832]
  unsigned short* ewb  = (unsigned short*)(ws + 23592960);   //  1,703,936  embW bf16 [1024][832]
  unsigned short* hwb  = (unsigned short*)(ws + 25296896);   //  2,097,152  headW bf16[1024][1024]
  float*          xemb = (float*)(ws + 27394048);            // 16,777,216  x_emb f32 [4096][1024]
  float*          h    = (float*)(ws + 44171264);            // 16,777,216  h f32     [4096][1024]
  unsigned short* hn   = (unsigned short*)(ws + 60948480);   //  8,388,608  ln(h) bf16[4096][1024]
  unsigned short* act  = (unsigned short*)(ws + 69337088);   // 33,554,432  ffn act   [4096][4096]
  unsigned short* hb   = (unsigned short*)(ws + 102891520);  //  8,388,608  h bf16    [4096][1024]
  unsigned short* P    = (unsigned short*)(ws + 111280128);  // 33,554,432  partials bf16 [4][4096][1024]
  const bool splitk = ws_size >= (size_t)144834560;
  const long PS = 4194304;  // partial stride in u16 elements (4096*1024)

  cvt_pad<<<dim3(4, 4096), 256, 0, stream>>>(W1_w, W1b, 4096, 1024, 1024);
  cvt_pad<<<dim3(16, 1024), 256, 0, stream>>>(W2_w, W2b, 1024, 4096, 4096);
  cvt_pad<<<dim3(4, 4096), 256, 0, stream>>>(x, xb, 4096, 784, 832);
  cvt_pad<<<dim3(4, 1024), 256, 0, stream>>>(embed_w, ewb, 1024, 784, 832);
  cvt_pad<<<dim3(4, 1024), 256, 0, stream>>>(head_w, hwb, 1000, 1024, 1024);

  // x_emb = x @ embed_w^T + embed_b ; h = x_emb   (K=832)
  gemm_bt<0, 128, 128, 64, 64, 256><<<dim3(8, 32), 256, 0, stream>>>(
      xb, ewb, 832, 832, 832, embed_b, 1024, 1024, 8, 4, 4, xemb, h, nullptr, nullptr);

  for (int s = 0; s < 30; s++) {
    if (splitk && s > 0)
      ln_bf16<1><<<4096, 256, 0, stream>>>(h, norm_w, norm_b, hn, xemb, W2_b, P, PS);
    else
      ln_bf16<0><<<4096, 256, 0, stream>>>(h, norm_w, norm_b, hn, nullptr, nullptr, nullptr, 0);

    // act = tanh(hn @ W1^T + b1): 128^2 tile, TWO waves of 64x128 (TH=128),
    // 42.7 FLOP/LDS-B; grid 1024 = 4 blocks/CU  [A/B test arm]
    gemm_bt<1, 128, 128, 64, 128, 128><<<dim3(32, 32), 128, 0, stream>>>(
        hn, W1b, 1024, 1024, 1024, W1_b, 4096, 4096, 8, 4, 16, nullptr, nullptr, act, nullptr);

    if (splitk) {
      // P[z] = act[:, z*1024:+1024] @ W2^T chunk (bf16, packed store):
      // r9-exact config  [control arm]
      gemm_bt<4, 128, 128, 64, 64, 256><<<dim3(8, 32, 4), 256, 0, stream>>>(
          act, W2b, 1024, 4096, 4096, nullptr, 1024, (int)PS, 8, 4, 4,
          nullptr, nullptr, P, nullptr);
    } else {
      // fallback: h = .5h + .5(act @ W2^T + b2 + xemb) direct RMW
      gemm_bt<2, 128, 64, 64, 32, 256><<<dim3(16, 32), 256, 0, stream>>>(
          act, W2b, 4096, 4096, 4096, W2_b, 1024, 1024, 8, 4, 8, h, nullptr, nullptr, xemb);
    }
  }

  if (splitk)
    cvt_h<1><<<4096, 256, 0, stream>>>(h, hb, xemb, W2_b, P, PS);
  else
    cvt_h<0><<<4096, 256, 0, stream>>>(h, hb, nullptr, nullptr, nullptr, 0);

  gemm_bt<3, 128, 128, 64, 64, 256><<<dim3(8, 32), 256, 0, stream>>>(
      hb, hwb, 1024, 1024, 1024, head_b, 1000, 1000, 8, 4, 4, (float*)d_out, nullptr, nullptr, nullptr);
}

// Round 12
// 2739.204 us; speedup vs baseline: 1.0863x; 1.0452x over previous
//
#include <hip/hip_runtime.h>
#include <math.h>

#define GAMMA 0.5f

typedef __bf16 bf16x8 __attribute__((ext_vector_type(8)));
typedef float  f32x4  __attribute__((ext_vector_type(4)));

__device__ __forceinline__ unsigned short f2bf(float f){
  union { float ff; unsigned u; } x; x.ff = f;
  return (unsigned short)((x.u + 0x7fffu + ((x.u >> 16) & 1u)) >> 16);
}

__device__ __forceinline__ float bf2f(unsigned short u){
  union { unsigned u; float f; } x; x.u = (unsigned)u << 16;
  return x.f;
}

__device__ __forceinline__ float fast_tanh(float v){
  float e = __expf(v + v);
  return 1.f - 2.f * __builtin_amdgcn_rcpf(e + 1.f);
}

__device__ __forceinline__ void gload16(const void* g, void* l){
  __builtin_amdgcn_global_load_lds((const __attribute__((address_space(1))) void*)g,
                                   (__attribute__((address_space(3))) void*)l,
                                   16, 0, 0);
}

// ============================================================================
// gemm_bt: 2-barrier single-buffer GEMM, C = A[M,Ktot]*B[N,Ktot]^T.
// blockIdx.z selects a K-chunk of length K (split-K). Tile BM x BN, BK=64,
// 256 thr = 4 waves 2x2, wave owns WM x WN, acc [WM/16][WN/16] f32x4.
//
// THIS IS THE MEASURED OPTIMUM (r9: 2770us total, twins 40.4us, MfmaUtil 33%).
// Explored and rejected (all HW-measured worse):
//  - D-ring counted-vmcnt (r1/r6), 8-phase 256^2 (r4): structure changes lose
//    because this problem's K=1024 chunks + 4 blk/CU live off wave overlap.
//  - 256x128 tile @ 2 blk/CU (r10: 43.9), 2-wave 64x128 @ 4 blk/CU (r11:
//    48.5): total waves/CU (16 here) dominates LDS-traffic ratio.
// PROVEN pieces:
//  - BK=64 dual-optimal LDS slot map: 16B chunk (row, kq), kq in 0..7:
//    slot = (row>>2)*32 + (row&3)*8 + ((kq>>2)^((row>>2)&1))*4 + ((kq&3)^(row&3))
//    STAGE: 8 consecutive threads = one FULL row x 128B (coalesced, full
//    L2-line; FETCH == unique bytes); ds_read_b128 0-conflict.
//  - LDS-packed bf16 epilogue (kills 1.9x write amplification).
// Epilogues:
//  MODE 0: F0=v; F1=v (f32)            MODE 3: masked f32 (head)
//  MODE 2: F0 = .5*F0 + .5*(v+R0)      (fallback path)
//  MODE 1: U0 = bf16(tanh(v+bias))     -- LDS-packed full rows
//  MODE 4: U0 = bf16(v), U0 += z*pstride ('nmax') -- LDS-packed
// ============================================================================
template<int MODE, int BM, int BN, int WM, int WN>
__global__ __launch_bounds__(256, 2)
void gemm_bt(const unsigned short* __restrict__ A,
             const unsigned short* __restrict__ B,
             int K, int lda, int ldb, const float* __restrict__ bias,
             int ldc, int nmax, int RM, int MR, int RN,
             float* __restrict__ F0, float* __restrict__ F1,
             unsigned short* __restrict__ U0,
             const float* __restrict__ R0)
{
  static_assert(BM / WM == 2 && BN / WN == 2, "4 waves arranged 2x2");
  constexpr int MI = WM / 16;
  constexpr int JN = WN / 16;
  const int bid = blockIdx.y * gridDim.x + blockIdx.x;
  const int xcd = bid & 7, kk = bid >> 3;
  const int m0 = ((xcd % MR) * RM + (kk % RM)) * BM;
  const int n0 = ((xcd / MR) * RN + (kk / RM)) * BN;
  const long kz = (long)blockIdx.z * K;
  A += kz; B += kz;
  if (MODE == 4) U0 += (long)blockIdx.z * (long)nmax;

  const int t = threadIdx.x, w = t >> 6, l = t & 63;

  constexpr int STG = (BM + BN) * 64;                         // staging u16
  constexpr int PCK = (MODE == 1 || MODE == 4) ? BM * BN : 0; // pack u16
  constexpr int SH  = STG > PCK ? STG : PCK;
  __shared__ __align__(16) unsigned short sh[SH];
  unsigned short* lgA = sh;            // [BM*64]  (BM rows x 8 chunks x 8 u16)
  unsigned short* lgB = sh + BM * 64;  // [BN*64]

  f32x4 acc[MI][JN];
  #pragma unroll
  for (int i = 0; i < MI; i++)
    #pragma unroll
    for (int j = 0; j < JN; j++) acc[i][j] = (f32x4){0.f, 0.f, 0.f, 0.f};

  const int wm = (w & 1) * WM, wn = (w >> 1) * WN;
  const int lr = l & 15, quad = l >> 4;
  // fragment-read slot offset within a 128-slot row-group (const per thread):
  const int fo0 = (lr >> 2) * 32 + (lr & 3) * 8 + ((lr >> 2) & 1) * 4 + (quad ^ (lr & 3));
  const int fo1 = fo0 ^ 4;

  // STAGE: thread c handles slot c; inverse map gives its global chunk:
  //   row = (c>>5)*4 + ((c>>3)&3)
  //   ko  = ((((c>>2)&1) ^ ((c>>5)&1))*4 + ((c&3) ^ ((c>>3)&3))) * 8
#define STAGE(kt) { \
    _Pragma("unroll") \
    for (int j = 0; j < BM / 32; j++) { \
      const int c = j * 256 + t; \
      const int a = (c >> 3) & 3; \
      const int row = (c >> 5) * 4 + a; \
      const int ko = ((((c >> 2) & 1) ^ ((c >> 5) & 1)) << 5) + (((c & 3) ^ a) << 3); \
      gload16(A + (long)(m0 + row) * lda + (kt) + ko, (char*)lgA + c * 16); \
    } \
    _Pragma("unroll") \
    for (int j = 0; j < BN / 32; j++) { \
      const int c = j * 256 + t; \
      const int a = (c >> 3) & 3; \
      const int row = (c >> 5) * 4 + a; \
      const int ko = ((((c >> 2) & 1) ^ ((c >> 5) & 1)) << 5) + (((c & 3) ^ a) << 3); \
      gload16(B + (long)(n0 + row) * ldb + (kt) + ko, (char*)lgB + c * 16); \
    } }

#define COMPUTE(fo) { \
    bf16x8 af[MI], bg[JN]; \
    _Pragma("unroll") \
    for (int i = 0; i < MI; i++) \
      af[i] = *(const bf16x8*)&lgA[((((wm >> 4) + i) << 7) + (fo)) * 8]; \
    _Pragma("unroll") \
    for (int j = 0; j < JN; j++) \
      bg[j] = *(const bf16x8*)&lgB[((((wn >> 4) + j) << 7) + (fo)) * 8]; \
    _Pragma("unroll") \
    for (int i = 0; i < MI; i++) \
      _Pragma("unroll") \
      for (int j = 0; j < JN; j++) \
        acc[i][j] = __builtin_amdgcn_mfma_f32_16x16x32_bf16(af[i], bg[j], acc[i][j], 0, 0, 0); \
  }

  const int NT = K >> 6;               // BK=64 steps (K multiple of 64)
  for (int tt = 0; tt < NT; ++tt) {
    __syncthreads();                   // prev COMPUTE's LDS reads done
    STAGE(tt * 64)
    __syncthreads();                   // compiler drains vmcnt: staged data ready
    COMPUTE(fo0)
    COMPUTE(fo1)
  }
#undef STAGE
#undef COMPUTE

  if constexpr (MODE == 1 || MODE == 4) {
    // ---- LDS-packed bf16 epilogue: assemble [BM][BN] tile, write full rows.
    __syncthreads();                   // last COMPUTE's reads done; reuse sh
    #pragma unroll
    for (int i = 0; i < MI; i++) {
      const int rb = wm + i * 16 + quad * 4;
      #pragma unroll
      for (int j = 0; j < JN; j++) {
        const int cl = wn + j * 16 + lr;
        const float bia = (MODE == 1) ? bias[n0 + cl] : 0.f;
        #pragma unroll
        for (int r = 0; r < 4; r++) {
          const float v = acc[i][j][r] + bia;
          sh[(rb + r) * BN + cl] = (MODE == 1) ? f2bf(fast_tanh(v)) : f2bf(v);
        }
      }
    }
    __syncthreads();
    constexpr int CPR = BN / 8;        // 16B chunks per row
    constexpr int RPP = 256 / CPR;     // rows per pass
    const int ch = t & (CPR - 1), rw = t / CPR;
    #pragma unroll
    for (int p = 0; p < BM / RPP; p++) {
      const int row = p * RPP + rw;
      *(bf16x8*)&U0[(long)(m0 + row) * ldc + n0 + ch * 8] =
          *(const bf16x8*)&sh[row * BN + ch * 8];
    }
  } else {
    #pragma unroll
    for (int i = 0; i < MI; i++) {
      const int mb = m0 + wm + i * 16 + quad * 4;
      #pragma unroll
      for (int j = 0; j < JN; j++) {
        const int n = n0 + wn + j * 16 + lr;
        float bia = 0.f;
        if (MODE == 3) { if (n < nmax) bia = bias[n]; } else { bia = bias[n]; }
        #pragma unroll
        for (int r = 0; r < 4; r++) {
          const long m = mb + r;
          const float v = acc[i][j][r] + bia;
          const long idx = m * (long)ldc + n;
          if (MODE == 0)      { F0[idx] = v; F1[idx] = v; }
          else if (MODE == 2) { F0[idx] = (1.f - GAMMA) * F0[idx] + GAMMA * (v + R0[idx]); }
          else                { if (n < nmax) F0[idx] = v; }
        }
      }
    }
  }
}

// LayerNorm over rows of 1024 fp32 -> bf16. COMB=1 first folds the split-K
// combine: h <- .5h + .5*(sum_z P[z] + b2 + xemb)  (P is bf16), writes h,
// then LNs the NEW h (matches reference step ordering; validated r3-r11).
template<int COMB>
__global__ __launch_bounds__(256)
void ln_bf16(float* __restrict__ h, const float* __restrict__ gw,
             const float* __restrict__ gb, unsigned short* __restrict__ o,
             const float* __restrict__ xemb, const float* __restrict__ b2,
             const unsigned short* __restrict__ P, long ps)
{
  const int row = blockIdx.x, t = threadIdx.x;
  const long base = (long)row * 1024;
  float4 v = ((const float4*)(h + base))[t];
  if (COMB) {
    const ushort4 q0 = *(const ushort4*)&P[base + 4 * t];
    const ushort4 q1 = *(const ushort4*)&P[ps + base + 4 * t];
    const ushort4 q2 = *(const ushort4*)&P[2 * ps + base + 4 * t];
    const ushort4 q3 = *(const ushort4*)&P[3 * ps + base + 4 * t];
    const float4 xe = ((const float4*)(xemb + base))[t];
    const float4 bb = ((const float4*)b2)[t];
    v.x = (1.f - GAMMA) * v.x + GAMMA * (bf2f(q0.x) + bf2f(q1.x) + bf2f(q2.x) + bf2f(q3.x) + xe.x + bb.x);
    v.y = (1.f - GAMMA) * v.y + GAMMA * (bf2f(q0.y) + bf2f(q1.y) + bf2f(q2.y) + bf2f(q3.y) + xe.y + bb.y);
    v.z = (1.f - GAMMA) * v.z + GAMMA * (bf2f(q0.z) + bf2f(q1.z) + bf2f(q2.z) + bf2f(q3.z) + xe.z + bb.z);
    v.w = (1.f - GAMMA) * v.w + GAMMA * (bf2f(q0.w) + bf2f(q1.w) + bf2f(q2.w) + bf2f(q3.w) + xe.w + bb.w);
    ((float4*)(h + base))[t] = v;
  }
  float s = v.x + v.y + v.z + v.w;
  float q = v.x * v.x + v.y * v.y + v.z * v.z + v.w * v.w;
  #pragma unroll
  for (int o2 = 32; o2 > 0; o2 >>= 1) { s += __shfl_xor(s, o2); q += __shfl_xor(q, o2); }
  __shared__ float rs[4], rq[4];
  if ((t & 63) == 0) { rs[t >> 6] = s; rq[t >> 6] = q; }
  __syncthreads();
  s = rs[0] + rs[1] + rs[2] + rs[3];
  q = rq[0] + rq[1] + rq[2] + rq[3];
  const float mu  = s * (1.f / 1024.f);
  const float inv = rsqrtf(q * (1.f / 1024.f) - mu * mu + 1e-5f);
  const float4 wv = ((const float4*)gw)[t];
  const float4 bv = ((const float4*)gb)[t];
  ushort4 u;
  u.x = f2bf((v.x - mu) * inv * wv.x + bv.x);
  u.y = f2bf((v.y - mu) * inv * wv.y + bv.y);
  u.z = f2bf((v.z - mu) * inv * wv.z + bv.z);
  u.w = f2bf((v.w - mu) * inv * wv.w + bv.w);
  ((ushort4*)(o + base))[t] = u;
}

// f32 -> bf16 with zero padding
__global__ __launch_bounds__(256)
void cvt_pad(const float* __restrict__ src, unsigned short* __restrict__ dst,
             int src_rows, int src_cols, int dst_cols)
{
  const int r = blockIdx.y;
  const int c = blockIdx.x * 256 + threadIdx.x;
  if (c >= dst_cols) return;
  unsigned short v = 0;
  if (r < src_rows && c < src_cols) v = f2bf(src[(long)r * src_cols + c]);
  dst[(long)r * dst_cols + c] = v;
}

// h fp32 -> bf16; COMB=1 applies the final split-K combine first (P bf16).
template<int COMB>
__global__ __launch_bounds__(256)
void cvt_h(const float* __restrict__ h, unsigned short* __restrict__ o,
           const float* __restrict__ xemb, const float* __restrict__ b2,
           const unsigned short* __restrict__ P, long ps)
{
  const long i = (long)blockIdx.x * 256 + threadIdx.x;
  float4 v = ((const float4*)h)[i];
  if (COMB) {
    const ushort4 q0 = *(const ushort4*)&P[4 * i];
    const ushort4 q1 = *(const ushort4*)&P[ps + 4 * i];
    const ushort4 q2 = *(const ushort4*)&P[2 * ps + 4 * i];
    const ushort4 q3 = *(const ushort4*)&P[3 * ps + 4 * i];
    const float4 xe = ((const float4*)xemb)[i];
    const float4 bb = ((const float4*)b2)[(int)(i & 255)];
    v.x = (1.f - GAMMA) * v.x + GAMMA * (bf2f(q0.x) + bf2f(q1.x) + bf2f(q2.x) + bf2f(q3.x) + xe.x + bb.x);
    v.y = (1.f - GAMMA) * v.y + GAMMA * (bf2f(q0.y) + bf2f(q1.y) + bf2f(q2.y) + bf2f(q3.y) + xe.y + bb.y);
    v.z = (1.f - GAMMA) * v.z + GAMMA * (bf2f(q0.z) + bf2f(q1.z) + bf2f(q2.z) + bf2f(q3.z) + xe.z + bb.z);
    v.w = (1.f - GAMMA) * v.w + GAMMA * (bf2f(q0.w) + bf2f(q1.w) + bf2f(q2.w) + bf2f(q3.w) + xe.w + bb.w);
  }
  ushort4 u;
  u.x = f2bf(v.x); u.y = f2bf(v.y); u.z = f2bf(v.z); u.w = f2bf(v.w);
  ((ushort4*)o)[i] = u;
}

extern "C" void kernel_launch(void* const* d_in, const int* in_sizes, int n_in,
                              void* d_out, int out_size, void* d_ws, size_t ws_size,
                              hipStream_t stream)
{
  const float* x       = (const float*)d_in[0];
  const float* embed_w = (const float*)d_in[1];
  const float* embed_b = (const float*)d_in[2];
  const float* W1_w    = (const float*)d_in[3];
  const float* W1_b    = (const float*)d_in[4];
  const float* W2_w    = (const float*)d_in[5];
  const float* W2_b    = (const float*)d_in[6];
  const float* norm_w  = (const float*)d_in[7];
  const float* norm_b  = (const float*)d_in[8];
  const float* head_w  = (const float*)d_in[9];
  const float* head_b  = (const float*)d_in[10];
  (void)in_sizes; (void)n_in; (void)out_size;

  // Workspace layout (x/embW K-padded to 832 = 13*64 for BK=64)
  char* ws = (char*)d_ws;
  unsigned short* W1b  = (unsigned short*)(ws);              //  8,388,608  W1 bf16   [4096][1024]
  unsigned short* W2b  = (unsigned short*)(ws + 8388608);    //  8,388,608  W2 bf16   [1024][4096]
  unsigned short* xb   = (unsigned short*)(ws + 16777216);   //  6,815,744  x bf16    [4096][832]
  unsigned short* ewb  = (unsigned short*)(ws + 23592960);   //  1,703,936  embW bf16 [1024][832]
  unsigned short* hwb  = (unsigned short*)(ws + 25296896);   //  2,097,152  headW bf16[1024][1024]
  float*          xemb = (float*)(ws + 27394048);            // 16,777,216  x_emb f32 [4096][1024]
  float*          h    = (float*)(ws + 44171264);            // 16,777,216  h f32     [4096][1024]
  unsigned short* hn   = (unsigned short*)(ws + 60948480);   //  8,388,608  ln(h) bf16[4096][1024]
  unsigned short* act  = (unsigned short*)(ws + 69337088);   // 33,554,432  ffn act   [4096][4096]
  unsigned short* hb   = (unsigned short*)(ws + 102891520);  //  8,388,608  h bf16    [4096][1024]
  unsigned short* P    = (unsigned short*)(ws + 111280128);  // 33,554,432  partials bf16 [4][4096][1024]
  const bool splitk = ws_size >= (size_t)144834560;
  const long PS = 4194304;  // partial stride in u16 elements (4096*1024)

  cvt_pad<<<dim3(4, 4096), 256, 0, stream>>>(W1_w, W1b, 4096, 1024, 1024);
  cvt_pad<<<dim3(16, 1024), 256, 0, stream>>>(W2_w, W2b, 1024, 4096, 4096);
  cvt_pad<<<dim3(4, 4096), 256, 0, stream>>>(x, xb, 4096, 784, 832);
  cvt_pad<<<dim3(4, 1024), 256, 0, stream>>>(embed_w, ewb, 1024, 784, 832);
  cvt_pad<<<dim3(4, 1024), 256, 0, stream>>>(head_w, hwb, 1000, 1024, 1024);

  // x_emb = x @ embed_w^T + embed_b ; h = x_emb   (K=832)
  gemm_bt<0, 128, 128, 64, 64><<<dim3(8, 32), 256, 0, stream>>>(
      xb, ewb, 832, 832, 832, embed_b, 1024, 1024, 8, 4, 4, xemb, h, nullptr, nullptr);

  for (int s = 0; s < 30; s++) {
    if (splitk && s > 0)
      ln_bf16<1><<<4096, 256, 0, stream>>>(h, norm_w, norm_b, hn, xemb, W2_b, P, PS);
    else
      ln_bf16<0><<<4096, 256, 0, stream>>>(h, norm_w, norm_b, hn, nullptr, nullptr, nullptr, 0);

    // act = tanh(hn @ W1^T + b1): 128^2, 1024 blocks (4/CU), packed store
    gemm_bt<1, 128, 128, 64, 64><<<dim3(32, 32), 256, 0, stream>>>(
        hn, W1b, 1024, 1024, 1024, W1_b, 4096, 4096, 8, 4, 16, nullptr, nullptr, act, nullptr);

    if (splitk) {
      // P[z] = act[:, z*1024:+1024] @ W2^T chunk (bf16, packed store):
      // grid m32 x n8 x z4 = 1024 blocks (4/CU)
      gemm_bt<4, 128, 128, 64, 64><<<dim3(8, 32, 4), 256, 0, stream>>>(
          act, W2b, 1024, 4096, 4096, nullptr, 1024, (int)PS, 8, 4, 4,
          nullptr, nullptr, P, nullptr);
    } else {
      // fallback: h = .5h + .5(act @ W2^T + b2 + xemb) direct RMW
      gemm_bt<2, 128, 64, 64, 32><<<dim3(16, 32), 256, 0, stream>>>(
          act, W2b, 4096, 4096, 4096, W2_b, 1024, 1024, 8, 4, 8, h, nullptr, nullptr, xemb);
    }
  }

  if (splitk)
    cvt_h<1><<<4096, 256, 0, stream>>>(h, hb, xemb, W2_b, P, PS);
  else
    cvt_h<0><<<4096, 256, 0, stream>>>(h, hb, nullptr, nullptr, nullptr, 0);

  gemm_bt<3, 128, 128, 64, 64><<<dim3(8, 32), 256, 0, stream>>>(
      hb, hwb, 1024, 1024, 1024, head_b, 1000, 1000, 8, 4, 4, (float*)d_out, nullptr, nullptr, nullptr);
}